// Round 1
// 2597.682 us; speedup vs baseline: 1.0093x; 1.0093x over previous
//
#include <hip/hip_runtime.h>

#define B 8
#define N 16384
#define C_IN 32
#define P 1024

// ---------------------------------------------------------------------------
// FPS: one block per batch, 1024 threads, 16 points/thread in registers.
// Bitwise-matches numpy: d = ((dx*dx + dy*dy) + dz*dz), no fma; argmax first-idx.
// Writes new_xyz (B,P,3) directly into d_out.
//
// R1: VGPR_Count=48 showed the compiler rematerialized px/py/pz from global
// every iteration (192KB/block/iter through L2). Pin them in VGPRs with an
// empty asm barrier + __launch_bounds__(1024,4) (128-VGPR cap, 1 block/CU).
// Also: within-thread tie-break (n < besti) is dead since n ascends with i;
// track 4-bit i via inline-const cndmask, form n once per iteration.
// ---------------------------------------------------------------------------
__global__ __launch_bounds__(1024, 4) void fps_kernel(
    const float* __restrict__ xyz, float* __restrict__ new_xyz)
{
  const int b = blockIdx.x;
  const int t = threadIdx.x;
  const float* xb = xyz + (size_t)b * (N * 3);

  float px[16], py[16], pz[16], dmin[16];
#pragma unroll
  for (int i = 0; i < 16; ++i) {
    int n = t + (i << 10);
    px[i] = xb[n * 3 + 0];
    py[i] = xb[n * 3 + 1];
    pz[i] = xb[n * 3 + 2];
    dmin[i] = 1e10f;
    // Opaque to the optimizer: forces px/py/pz to live in VGPRs instead of
    // being re-loaded from global memory every one of the 1023 iterations.
    asm volatile("" : "+v"(px[i]), "+v"(py[i]), "+v"(pz[i]));
  }

  __shared__ float rv[2][16];
  __shared__ int   ri[2][16];

  int sel = 0;
  for (int iter = 0; iter < P; ++iter) {
    float cx = xb[sel * 3 + 0];
    float cy = xb[sel * 3 + 1];
    float cz = xb[sel * 3 + 2];
    if (t == 0) {
      size_t o = ((size_t)b * P + iter) * 3;
      new_xyz[o + 0] = cx;
      new_xyz[o + 1] = cy;
      new_xyz[o + 2] = cz;
    }
    if (iter == P - 1) break;

    float bestv = -1.0f;
    int   bi = 0;
#pragma unroll
    for (int i = 0; i < 16; ++i) {
      float dx = __fsub_rn(px[i], cx);
      float dy = __fsub_rn(py[i], cy);
      float dz = __fsub_rn(pz[i], cz);
      float d  = __fadd_rn(__fadd_rn(__fmul_rn(dx, dx), __fmul_rn(dy, dy)),
                           __fmul_rn(dz, dz));
      float dm = fminf(dmin[i], d);
      dmin[i] = dm;
      // n = t + (i<<10) ascends with i, so first-max == strict '>' here;
      // the (dm == bestv && n < besti) clause of the original is dead.
      bool better = (dm > bestv);
      bestv = better ? dm : bestv;
      bi    = better ? i  : bi;
    }
    int besti = t + (bi << 10);
    // wave-level (val,idx) argmax reduce, tie -> smaller idx (numpy first-max)
#pragma unroll
    for (int off = 32; off > 0; off >>= 1) {
      float ov = __shfl_xor(bestv, off);
      int   oi = __shfl_xor(besti, off);
      bool better = (ov > bestv) || (ov == bestv && oi < besti);
      bestv = better ? ov : bestv;
      besti = better ? oi : besti;
    }
    int parity = iter & 1;
    if ((t & 63) == 0) { rv[parity][t >> 6] = bestv; ri[parity][t >> 6] = besti; }
    __syncthreads();
    // all threads reduce the 16 wave results (shuffle within 16-lane groups)
    float gv = rv[parity][t & 15];
    int   gi = ri[parity][t & 15];
#pragma unroll
    for (int off = 8; off > 0; off >>= 1) {
      float ov = __shfl_xor(gv, off);
      int   oi = __shfl_xor(gi, off);
      bool better = (ov > gv) || (ov == gv && oi < gi);
      gv = better ? ov : gv;
      gi = better ? oi : gi;
    }
    sel = gi;
  }
}

// ---------------------------------------------------------------------------
// Ball query, both radii in one pass. One wave per (b,p). Reproduces the
// reference's gemm-form dist2 bitwise: (qq + xx) - 2*((cx*x+cy*y)+cz*z).
// First-nsample-in-index-order via ballot + prefix popcount; pad = first hit.
// ---------------------------------------------------------------------------
__global__ __launch_bounds__(256) void ballq_kernel(
    const float* __restrict__ xyz, const float* __restrict__ new_xyz,
    int* __restrict__ idx0, int* __restrict__ idx1)
{
  const int wid  = blockIdx.x * 4 + (threadIdx.x >> 6);
  const int lane = threadIdx.x & 63;
  const int b = wid >> 10;
  const int p = wid & (P - 1);
  const float* xb = xyz + (size_t)b * (N * 3);
  const size_t bp = (size_t)b * P + p;
  const float cx = new_xyz[bp * 3 + 0];
  const float cy = new_xyz[bp * 3 + 1];
  const float cz = new_xyz[bp * 3 + 2];
  const float qv = __fadd_rn(__fadd_rn(__fmul_rn(cx, cx), __fmul_rn(cy, cy)),
                             __fmul_rn(cz, cz));
  int* __restrict__ o0 = idx0 + bp * 16;
  int* __restrict__ o1 = idx1 + bp * 32;

  int c0 = 0, c1 = 0, f0 = 0, f1 = 0;
  const unsigned long long below = (1ull << lane) - 1ull;

  for (int base = 0; base < N; base += 64) {
    int n = base + lane;
    float x = xb[n * 3 + 0], y = xb[n * 3 + 1], z = xb[n * 3 + 2];
    float xxv = __fadd_rn(__fadd_rn(__fmul_rn(x, x), __fmul_rn(y, y)),
                          __fmul_rn(z, z));
    float dot = __fadd_rn(__fadd_rn(__fmul_rn(cx, x), __fmul_rn(cy, y)),
                          __fmul_rn(cz, z));
    float d2 = __fsub_rn(__fadd_rn(qv, xxv), __fmul_rn(2.0f, dot));
    unsigned long long m0 = __ballot(d2 < 0.25f);
    unsigned long long m1 = __ballot(d2 < 1.0f);
    if (c0 == 0 && m0) f0 = base + __builtin_ctzll(m0);
    if (c1 == 0 && m1) f1 = base + __builtin_ctzll(m1);
    if ((m0 >> lane) & 1ull) {
      int pos = c0 + (int)__builtin_popcountll(m0 & below);
      if (pos < 16) o0[pos] = n;
    }
    if ((m1 >> lane) & 1ull) {
      int pos = c1 + (int)__builtin_popcountll(m1 & below);
      if (pos < 32) o1[pos] = n;
    }
    c0 = min(16, c0 + (int)__builtin_popcountll(m0));
    c1 = min(32, c1 + (int)__builtin_popcountll(m1));
    if (c0 >= 16 && c1 >= 32) break;
  }
  for (int s = c0 + lane; s < 16; s += 64) o0[s] = f0;
  for (int s = c1 + lane; s < 32; s += 64) o1[s] = f1;
}

// ---------------------------------------------------------------------------
// Fused grouping + conv1(+BN+ReLU) + conv2(+BN+ReLU) + max over samples.
// Block = 256 threads handles 8 points; weights staged in LDS once per block.
// out layout: (B, 192, P) at d_out + B*P*3, branch writes CH_OFF..CH_OFF+C2.
// ---------------------------------------------------------------------------
template <int S, int C1, int C2, int CH_OFF>
__global__ __launch_bounds__(256) void mlp_kernel(
    const float* __restrict__ xyz, const float* __restrict__ feats,
    const float* __restrict__ new_xyz, const int* __restrict__ idx,
    const float* __restrict__ w1, const float* __restrict__ s1,
    const float* __restrict__ b1, const float* __restrict__ w2,
    const float* __restrict__ s2, const float* __restrict__ b2,
    float* __restrict__ out)
{
  static_assert((C1 * S) % 256 == 0 && (C2 * S) % 256 == 0, "mapping");
  __shared__ float wl1[35][C1];     // wl1[c][o] = w1[o][c]
  __shared__ float wl2[C1][C2];     // wl2[c][o] = w2[o][c]
  __shared__ float sb1[2][C1];
  __shared__ float sb2[2][C2];
  __shared__ float xs[35][S];
  __shared__ float o1s[C1][S];
  __shared__ float pm[256];

  const int tid = threadIdx.x;
  for (int i = tid; i < 35 * C1; i += 256) {
    int o = i % C1, c = i / C1;
    wl1[c][o] = w1[o * 35 + c];
  }
  for (int i = tid; i < C1 * C2; i += 256) {
    int o = i % C2, c = i / C2;
    wl2[c][o] = w2[o * C1 + c];
  }
  if (tid < C1) { sb1[0][tid] = s1[tid]; sb1[1][tid] = b1[tid]; }
  if (tid < C2) { sb2[0][tid] = s2[tid]; sb2[1][tid] = b2[tid]; }

  const int b  = blockIdx.x / (P / 8);
  const int p0 = (blockIdx.x % (P / 8)) * 8;
  const float* xb = xyz + (size_t)b * (N * 3);
  const float* fb = feats + (size_t)b * (C_IN * N);
  __syncthreads();

  for (int pi = 0; pi < 8; ++pi) {
    const int p = p0 + pi;
    const size_t bp = (size_t)b * P + p;
    const int* ip = idx + bp * S;
    const float cx = new_xyz[bp * 3 + 0];
    const float cy = new_xyz[bp * 3 + 1];
    const float cz = new_xyz[bp * 3 + 2];
    // gather grouped input (35, S): xyz-diff channels 0..2, features 3..34
    for (int i = tid; i < 35 * S; i += 256) {
      int c = i / S, s = i % S;
      int n = ip[s];
      float v;
      if (c == 0)      v = xb[n * 3 + 0] - cx;
      else if (c == 1) v = xb[n * 3 + 1] - cy;
      else if (c == 2) v = xb[n * 3 + 2] - cz;
      else             v = fb[(size_t)(c - 3) * N + n];
      xs[c][s] = v;
    }
    __syncthreads();
    // layer 1: out1[o][s] = relu(dot(w1[o], x[:,s]) * s1[o] + b1[o])
    {
      constexpr int OPT = (C1 * S) / 256;
      const int s  = tid % S;
      const int ob = (tid / S) * OPT;
      float acc[OPT];
#pragma unroll
      for (int j = 0; j < OPT; ++j) acc[j] = 0.0f;
      for (int c = 0; c < 35; ++c) {
        float xv = xs[c][s];
#pragma unroll
        for (int j = 0; j < OPT; ++j) acc[j] = fmaf(xv, wl1[c][ob + j], acc[j]);
      }
#pragma unroll
      for (int j = 0; j < OPT; ++j) {
        float v = fmaf(acc[j], sb1[0][ob + j], sb1[1][ob + j]);
        o1s[ob + j][s] = fmaxf(v, 0.0f);
      }
    }
    __syncthreads();
    // layer 2 + max over s
    {
      constexpr int NS = (C2 * S) / 256;
      const int o2 = tid % C2;
      const int sb = (tid / C2) * NS;
      float acc[NS];
#pragma unroll
      for (int j = 0; j < NS; ++j) acc[j] = 0.0f;
      for (int c = 0; c < C1; ++c) {
        float wv = wl2[c][o2];
#pragma unroll
        for (int j = 0; j < NS; ++j) acc[j] = fmaf(wv, o1s[c][sb + j], acc[j]);
      }
      const float scale = sb2[0][o2], bias = sb2[1][o2];
      float m = 0.0f;  // relu floor: max over relu(v) == max(0, max v)
#pragma unroll
      for (int j = 0; j < NS; ++j) {
        float v = fmaf(acc[j], scale, bias);
        m = fmaxf(m, v);
      }
      pm[tid] = m;
      __syncthreads();
      if (tid < C2) {
        float mm = pm[tid];
#pragma unroll
        for (int g = 1; g < 256 / C2; ++g) mm = fmaxf(mm, pm[tid + g * C2]);
        out[((size_t)b * 192 + CH_OFF + tid) * P + p] = mm;
      }
    }
    __syncthreads();
  }
}

extern "C" void kernel_launch(void* const* d_in, const int* in_sizes, int n_in,
                              void* d_out, int out_size, void* d_ws, size_t ws_size,
                              hipStream_t stream) {
  const float* xyz   = (const float*)d_in[0];
  const float* feats = (const float*)d_in[1];
  const float* w0_0 = (const float*)d_in[2];
  const float* s0_0 = (const float*)d_in[3];
  const float* b0_0 = (const float*)d_in[4];
  const float* w0_1 = (const float*)d_in[5];
  const float* s0_1 = (const float*)d_in[6];
  const float* b0_1 = (const float*)d_in[7];
  const float* w1_0 = (const float*)d_in[8];
  const float* s1_0 = (const float*)d_in[9];
  const float* b1_0 = (const float*)d_in[10];
  const float* w1_1 = (const float*)d_in[11];
  const float* s1_1 = (const float*)d_in[12];
  const float* b1_1 = (const float*)d_in[13];

  float* out      = (float*)d_out;
  float* new_xyz  = out;                 // (B,P,3)
  float* feat_out = out + (size_t)B * P * 3;  // (B,192,P)

  char* w = (char*)d_ws;
  int* idx0 = (int*)w; w += (size_t)B * P * 16 * sizeof(int);
  int* idx1 = (int*)w; w += (size_t)B * P * 32 * sizeof(int);

  fps_kernel<<<dim3(B), dim3(1024), 0, stream>>>(xyz, new_xyz);
  ballq_kernel<<<dim3(B * P / 4), dim3(256), 0, stream>>>(xyz, new_xyz, idx0, idx1);
  mlp_kernel<16, 32, 64, 0><<<dim3(B * P / 8), dim3(256), 0, stream>>>(
      xyz, feats, new_xyz, idx0, w0_0, s0_0, b0_0, w0_1, s0_1, b0_1, feat_out);
  mlp_kernel<32, 64, 128, 64><<<dim3(B * P / 8), dim3(256), 0, stream>>>(
      xyz, feats, new_xyz, idx1, w1_0, s1_0, b1_0, w1_1, s1_1, b1_1, feat_out);
}